// Round 1
// baseline (1752.496 us; speedup 1.0000x reference)
//
#include <hip/hip_runtime.h>
#include <cstdint>

#define NTHREADS 256
#define TBL_SIZE (1u << 19)
#define HIDDEN 64

struct Levels { float scale[16]; int res[16]; int dense[16]; };
constexpr Levels make_levels() {
    Levels L{};
    double s = 16.0;
    for (int l = 0; l < 16; ++l) {
        double sc = s - 1.0;
        L.scale[l] = (float)sc;
        int fi = (int)sc;
        int res = fi + (((double)fi < sc) ? 1 : 0) + 1;   // ceil(sc)+1
        L.res[l] = res;
        L.dense[l] = ((long long)res * res * res <= (long long)TBL_SIZE) ? 1 : 0;
        s *= 1.3819;
    }
    return L;
}
constexpr Levels LV = make_levels();

__global__ __launch_bounds__(NTHREADS) void sdf_tcnn_fused(
    const float* __restrict__ x,
    const float* __restrict__ table,
    const float* __restrict__ W1, const float* __restrict__ b1,
    const float* __restrict__ W2, const float* __restrict__ b2,
    const float* __restrict__ W3, const float* __restrict__ b3,
    float* __restrict__ out, int n)
{
    __shared__ float sW1[32 * 64];
    __shared__ float sW2[64 * 64];
    __shared__ float sB1[64];
    __shared__ float sB2[64];
    __shared__ float sW3[64];
    __shared__ float sB3;

    for (int i = threadIdx.x; i < 32 * 64; i += NTHREADS) sW1[i] = W1[i];
    for (int i = threadIdx.x; i < 64 * 64; i += NTHREADS) sW2[i] = W2[i];
    if (threadIdx.x < 64) {
        sB1[threadIdx.x] = b1[threadIdx.x];
        sB2[threadIdx.x] = b2[threadIdx.x];
        sW3[threadIdx.x] = W3[threadIdx.x];
    }
    if (threadIdx.x == 0) sB3 = b3[0];
    __syncthreads();

    const int i = blockIdx.x * NTHREADS + threadIdx.x;
    if (i >= n) return;

    const float xi = x[3 * i + 0];
    const float yi = x[3 * i + 1];
    const float zi = x[3 * i + 2];
    const float u = (xi + 1.0f) * 0.5f;
    const float v = (yi + 1.0f) * 0.5f;
    const float w = (zi + 1.0f) * 0.5f;

    // h1 accumulates layer-1 pre-activation; layer-1 is fused into the level loop.
    float h1[HIDDEN];
    #pragma unroll
    for (int j = 0; j < HIDDEN; ++j) h1[j] = sB1[j];

    #pragma unroll
    for (int l = 0; l < 16; ++l) {
        const float sc = LV.scale[l];
        const int res = LV.res[l];
        const float pu = u * sc + 0.5f;
        const float pv = v * sc + 0.5f;
        const float pw = w * sc + 0.5f;
        const float fu = floorf(pu), fv = floorf(pv), fw = floorf(pw);
        const float wu = pu - fu, wv = pv - fv, ww = pw - fw;
        const int iu = (int)fu, iv = (int)fv, iw = (int)fw;

        const float2* tl = (const float2*)(table + (size_t)l * TBL_SIZE * 2);

        // compute the 8 corner indices first, then issue all 8 loads (ILP)
        int idx[8];
        #pragma unroll
        for (int b = 0; b < 8; ++b) {
            const int o0 = (b >> 2) & 1, o1 = (b >> 1) & 1, o2 = b & 1;
            if (LV.dense[l]) {
                idx[b] = (iu + o0) + (iv + o1) * res + (iw + o2) * (res * res);
            } else {
                const uint32_t c0 = (uint32_t)(iu + o0);
                const uint32_t c1 = (uint32_t)(iv + o1);
                const uint32_t c2 = (uint32_t)(iw + o2);
                const uint32_t h = c0 ^ (c1 * 2654435761u) ^ (c2 * 805459861u);
                idx[b] = (int)(h & (TBL_SIZE - 1u));
            }
        }
        float2 cf[8];
        #pragma unroll
        for (int b = 0; b < 8; ++b) cf[b] = tl[idx[b]];

        float f0 = 0.0f, f1 = 0.0f;
        #pragma unroll
        for (int b = 0; b < 8; ++b) {
            const int o0 = (b >> 2) & 1, o1 = (b >> 1) & 1, o2 = b & 1;
            const float wt = (o0 ? wu : 1.0f - wu) *
                             (o1 ? wv : 1.0f - wv) *
                             (o2 ? ww : 1.0f - ww);
            f0 = fmaf(cf[b].x, wt, f0);
            f1 = fmaf(cf[b].y, wt, f1);
        }

        // fused layer-1: h1 += f0 * W1[2l,:] + f1 * W1[2l+1,:]
        #pragma unroll
        for (int j = 0; j < HIDDEN; j += 4) {
            const float4 wa = *(const float4*)&sW1[(2 * l) * HIDDEN + j];
            const float4 wb = *(const float4*)&sW1[(2 * l + 1) * HIDDEN + j];
            h1[j + 0] = fmaf(f0, wa.x, fmaf(f1, wb.x, h1[j + 0]));
            h1[j + 1] = fmaf(f0, wa.y, fmaf(f1, wb.y, h1[j + 1]));
            h1[j + 2] = fmaf(f0, wa.z, fmaf(f1, wb.z, h1[j + 2]));
            h1[j + 3] = fmaf(f0, wa.w, fmaf(f1, wb.w, h1[j + 3]));
        }
    }

    // ReLU layer 1
    #pragma unroll
    for (int j = 0; j < HIDDEN; ++j) h1[j] = fmaxf(h1[j], 0.0f);

    // layers 2+3 fused: out = b3 + sum_j relu(b2[j] + sum_k h1[k]*W2[k,j]) * W3[j]
    float acc = sB3;
    #pragma unroll
    for (int j = 0; j < HIDDEN; j += 4) {
        float t0 = sB2[j + 0], t1 = sB2[j + 1], t2 = sB2[j + 2], t3 = sB2[j + 3];
        #pragma unroll 8
        for (int k = 0; k < HIDDEN; ++k) {
            const float4 wr = *(const float4*)&sW2[k * HIDDEN + j];
            const float hk = h1[k];
            t0 = fmaf(hk, wr.x, t0);
            t1 = fmaf(hk, wr.y, t1);
            t2 = fmaf(hk, wr.z, t2);
            t3 = fmaf(hk, wr.w, t3);
        }
        acc = fmaf(fmaxf(t0, 0.0f), sW3[j + 0], acc);
        acc = fmaf(fmaxf(t1, 0.0f), sW3[j + 1], acc);
        acc = fmaf(fmaxf(t2, 0.0f), sW3[j + 2], acc);
        acc = fmaf(fmaxf(t3, 0.0f), sW3[j + 3], acc);
    }

    out[i] = acc;
}

extern "C" void kernel_launch(void* const* d_in, const int* in_sizes, int n_in,
                              void* d_out, int out_size, void* d_ws, size_t ws_size,
                              hipStream_t stream) {
    const float* x     = (const float*)d_in[0];
    const float* table = (const float*)d_in[1];
    const float* W1    = (const float*)d_in[2];
    const float* b1    = (const float*)d_in[3];
    const float* W2    = (const float*)d_in[4];
    const float* b2    = (const float*)d_in[5];
    const float* W3    = (const float*)d_in[6];
    const float* b3    = (const float*)d_in[7];
    float* out = (float*)d_out;

    const int n = in_sizes[0] / 3;
    dim3 grid((n + NTHREADS - 1) / NTHREADS);
    hipLaunchKernelGGL(sdf_tcnn_fused, grid, dim3(NTHREADS), 0, stream,
                       x, table, W1, b1, W2, b2, W3, b3, out, n);
}